// Round 1
// baseline (78.998 us; speedup 1.0000x reference)
//
#include <hip/hip_runtime.h>
#include <hip/hip_bf16.h>

// Problem constants (fixed by setup_inputs)
#define M_PTS   1024
#define B_SZ    2
#define NC      64
#define KS      13
#define NA      20
#define KA      (KS * NA)      // 260
#define DIM_OUT 64

static constexpr float R2       = 0.4f * 0.4f;   // 0.16
static constexpr float INV2SIG  = 6.25f;         // 1 / (2 * 0.08)

__global__ __launch_bounds__(256)
void KernelPropagation_24206435681031_kernel(const float* __restrict__ frag,    // (M,3)
                                             const float* __restrict__ clouds,  // (B,3,NC)
                                             const float* __restrict__ kernels, // (KS,NA,3)
                                             const float* __restrict__ W,       // (DIM_OUT,KS)
                                             float* __restrict__ out)           // (B,DIM_OUT,NC,NA)
{
    const int bc = blockIdx.x;         // 0..B*NC-1
    const int b  = bc / NC;
    const int n  = bc % NC;
    const int tid = threadIdx.x;

    // center coords: clouds[b][d][n]
    const float cx = clouds[(b * 3 + 0) * NC + n];
    const float cy = clouds[(b * 3 + 1) * NC + n];
    const float cz = clouds[(b * 3 + 2) * NC + n];

    __shared__ float px[M_PTS], py[M_PTS], pz[M_PTS];
    __shared__ float kpx[KA], kpy[KA], kpz[KA];
    __shared__ float acc[KA];
    __shared__ int   cnt;

    if (tid == 0) cnt = 0;

    // kernel positions for this center
    for (int i = tid; i < KA; i += 256) {
        kpx[i] = cx + kernels[i * 3 + 0];
        kpy[i] = cy + kernels[i * 3 + 1];
        kpz[i] = cz + kernels[i * 3 + 2];
    }
    __syncthreads();

    // ball query + compaction of in-ball points into LDS
    for (int i = tid; i < M_PTS; i += 256) {
        const float x = frag[i * 3 + 0];
        const float y = frag[i * 3 + 1];
        const float z = frag[i * 3 + 2];
        const float dx = x - cx, dy = y - cy, dz = z - cz;
        const float d2 = dx * dx + dy * dy + dz * dz;
        if (d2 < R2) {
            const int idx = atomicAdd(&cnt, 1);
            px[idx] = x; py[idx] = y; pz[idx] = z;
        }
    }
    __syncthreads();

    const int   npts = cnt;
    const float inv  = 1.0f / ((float)npts + 1.0f);

    // RBF accumulation: each thread owns (k,a) pairs tid, tid+256, ...
    for (int i = tid; i < KA; i += 256) {
        const float kx = kpx[i], ky = kpy[i], kz = kpz[i];
        float s = 0.0f;
        for (int j = 0; j < npts; ++j) {
            const float dx = px[j] - kx;
            const float dy = py[j] - ky;
            const float dz = pz[j] - kz;
            const float d2 = dx * dx + dy * dy + dz * dz;
            s += __expf(-d2 * INV2SIG);
        }
        acc[i] = s * inv;   // wts[b, k, n, a] with i = k*NA + a
    }
    __syncthreads();

    // epilogue: feats[b, o, n, a] = sum_k W[o,k] * acc[k*NA + a]
    for (int i = tid; i < DIM_OUT * NA; i += 256) {
        const int o = i / NA;
        const int a = i % NA;
        float f = 0.0f;
#pragma unroll
        for (int k = 0; k < KS; ++k)
            f += W[o * KS + k] * acc[k * NA + a];
        out[((b * DIM_OUT + o) * NC + n) * NA + a] = f;
    }
}

extern "C" void kernel_launch(void* const* d_in, const int* in_sizes, int n_in,
                              void* d_out, int out_size, void* d_ws, size_t ws_size,
                              hipStream_t stream) {
    const float* frag    = (const float*)d_in[0];   // (1024,3)
    const float* clouds  = (const float*)d_in[1];   // (2,3,64)
    const float* kernels = (const float*)d_in[2];   // (13,20,3)
    const float* W       = (const float*)d_in[3];   // (64,13)
    float* out = (float*)d_out;                     // (2,64,64,20)

    (void)in_sizes; (void)n_in; (void)out_size; (void)d_ws; (void)ws_size;

    KernelPropagation_24206435681031_kernel<<<B_SZ * NC, 256, 0, stream>>>(
        frag, clouds, kernels, W, out);
}

// Round 2
// 72.977 us; speedup vs baseline: 1.0825x; 1.0825x over previous
//
#include <hip/hip_runtime.h>
#include <hip/hip_bf16.h>

// Problem constants (fixed by setup_inputs)
#define M_PTS   1024
#define B_SZ    2
#define NC      64
#define KS      13
#define NA      20
#define KA      (KS * NA)      // 260
#define DIM_OUT 64
#define NTHREADS 320           // 5 waves: one (k,a) item per thread for 260 items

static constexpr float R2    = 0.4f * 0.4f;                          // 0.16
static constexpr float C2SIG = 6.25f * 1.44269504088896340736f;      // (1/(2*sigma)) * log2(e)

__global__ __launch_bounds__(NTHREADS)
void KernelPropagation_24206435681031_kernel(const float* __restrict__ frag,    // (M,3)
                                             const float* __restrict__ clouds,  // (B,3,NC)
                                             const float* __restrict__ kernels, // (KS,NA,3)
                                             const float* __restrict__ W,       // (DIM_OUT,KS)
                                             float* __restrict__ out)           // (B,DIM_OUT,NC,NA)
{
    const int bc   = blockIdx.x;        // 0..B*NC-1
    const int b    = bc / NC;
    const int n    = bc % NC;
    const int tid  = threadIdx.x;
    const int lane = tid & 63;

    __shared__ float4 pf[M_PTS];            // compacted points: (x, y, z, -C*|p|^2)
    __shared__ float  acc[KA];
    __shared__ float  Wl[DIM_OUT * KS];
    __shared__ int    cnt;

    const float cx = clouds[(b * 3 + 0) * NC + n];
    const float cy = clouds[(b * 3 + 1) * NC + n];
    const float cz = clouds[(b * 3 + 2) * NC + n];

    // Per-thread rotated kernel point, prescaled for the exp2 inner loop:
    //   w = exp2( -C*|p|^2  +  2C*(p . k)  +  (-C*|k|^2) )
    //     = exp2( p.w_term + dot(p.xyz, k2) ) * ek
    float kx2 = 0.f, ky2 = 0.f, kz2 = 0.f, ek = 0.f;
    if (tid < KA) {
        const float kx = cx + kernels[tid * 3 + 0];
        const float ky = cy + kernels[tid * 3 + 1];
        const float kz = cz + kernels[tid * 3 + 2];
        const float pn2 = kx * kx + ky * ky + kz * kz;
        ek  = exp2f(-C2SIG * pn2);
        kx2 = (2.0f * C2SIG) * kx;
        ky2 = (2.0f * C2SIG) * ky;
        kz2 = (2.0f * C2SIG) * kz;
    }

    // Stage W in LDS (64x13 floats)
    for (int i = tid; i < DIM_OUT * KS; i += NTHREADS) Wl[i] = W[i];

    if (tid == 0) cnt = 0;
    __syncthreads();

    // Ball query + ballot-based compaction (one LDS atomic per wave per chunk)
    for (int base = 0; base < M_PTS; base += NTHREADS) {
        const int i = base + tid;
        bool  in = false;
        float x = 0.f, y = 0.f, z = 0.f, af = 0.f;
        if (i < M_PTS) {
            x = frag[i * 3 + 0];
            y = frag[i * 3 + 1];
            z = frag[i * 3 + 2];
            const float dx = x - cx, dy = y - cy, dz = z - cz;
            in = (dx * dx + dy * dy + dz * dz) < R2;
            af = -C2SIG * (x * x + y * y + z * z);
        }
        const unsigned long long mask = __ballot(in);
        const int tot = __popcll(mask);
        const int pre = __popcll(mask & ((1ull << lane) - 1ull));
        int wbase = 0;
        if (lane == 0 && tot) wbase = atomicAdd(&cnt, tot);
        wbase = __shfl(wbase, 0, 64);
        if (in) pf[wbase + pre] = make_float4(x, y, z, af);
    }
    __syncthreads();

    const int   npts = cnt;
    const float inv  = 1.0f / ((float)npts + 1.0f);

    // RBF accumulation: one (k,a) per thread, broadcast LDS reads over points
    if (tid < KA) {
        float s = 0.0f;
        int j = 0;
        for (; j + 1 < npts; j += 2) {
            const float4 p0 = pf[j];
            const float4 p1 = pf[j + 1];
            float t0 = p0.x * kx2;
            t0 = fmaf(p0.y, ky2, t0);
            t0 = fmaf(p0.z, kz2, t0);
            t0 += p0.w;
            float t1 = p1.x * kx2;
            t1 = fmaf(p1.y, ky2, t1);
            t1 = fmaf(p1.z, kz2, t1);
            t1 += p1.w;
            s = fmaf(ek, exp2f(t0), s);
            s = fmaf(ek, exp2f(t1), s);
        }
        if (j < npts) {
            const float4 p0 = pf[j];
            float t0 = p0.x * kx2;
            t0 = fmaf(p0.y, ky2, t0);
            t0 = fmaf(p0.z, kz2, t0);
            t0 += p0.w;
            s = fmaf(ek, exp2f(t0), s);
        }
        acc[tid] = s * inv;    // wts[b, k, n, a], tid = k*NA + a
    }
    __syncthreads();

    // Epilogue: feats[b, o, n, a] = sum_k W[o,k] * acc[k*NA + a]   (1280 = 4*320 items)
    for (int i = tid; i < DIM_OUT * NA; i += NTHREADS) {
        const int o = i / NA;
        const int a = i % NA;
        float f = 0.0f;
#pragma unroll
        for (int k = 0; k < KS; ++k)
            f = fmaf(Wl[o * KS + k], acc[k * NA + a], f);
        out[((b * DIM_OUT + o) * NC + n) * NA + a] = f;
    }
}

extern "C" void kernel_launch(void* const* d_in, const int* in_sizes, int n_in,
                              void* d_out, int out_size, void* d_ws, size_t ws_size,
                              hipStream_t stream) {
    const float* frag    = (const float*)d_in[0];   // (1024,3)
    const float* clouds  = (const float*)d_in[1];   // (2,3,64)
    const float* kernels = (const float*)d_in[2];   // (13,20,3)
    const float* W       = (const float*)d_in[3];   // (64,13)
    float* out = (float*)d_out;                     // (2,64,64,20)

    (void)in_sizes; (void)n_in; (void)out_size; (void)d_ws; (void)ws_size;

    KernelPropagation_24206435681031_kernel<<<B_SZ * NC, NTHREADS, 0, stream>>>(
        frag, clouds, kernels, W, out);
}